// Round 13
// baseline (62.915 us; speedup 1.0000x reference)
//
#include <hip/hip_runtime.h>
#include <math.h>

// AWLoss closed-form: f = 24 - (0.5/511^2) * sum_c S1_c^2 / S2_c
// S1 = sum wgt*Re(F), S2 = sum wgt*|F|^2 over half-spectrum k1 in [0,511),
// k2 in [0,256), wgt = 1 for k2==0 else 2, F = conj(X)Y / |X|^2
// (1e-9 pre-whitening is < 1e-12 relative to |X|^2 ~ 1e4 -> dropped).
// X = DFT2(pad(target)), Y = DFT2(pad(recon)), pad offset 127.
//
// Round-13: 3 dispatches (stage1, stage2, finalize). The twiddle fragment
// table is GONE -- each wave generates its 2 stationary twiddle tiles in
// registers via complex-rotation recurrence (3 sincosf + 64 rotations; mod-511
// wrap is automatic). R12's compute structures untouched; sacc zeroing merged
// into stage1 block 0.

#define NCH 48
#define PADOFF 127
#define TWO_PI_F 6.283185307179586f

typedef float f32x4 __attribute__((ext_vector_type(4)));
typedef short s16x8 __attribute__((ext_vector_type(8)));
typedef unsigned short u16;

typedef __attribute__((address_space(1))) const unsigned char* gas_p;
typedef __attribute__((address_space(3))) unsigned char* las_p;

union frag_u { u16 u[8]; s16x8 v; };

__device__ __forceinline__ u16 f2bf(float f) {
    union { float f; unsigned u; } x; x.f = f;
    unsigned r = x.u + 0x7FFFu + ((x.u >> 16) & 1u);
    return (u16)(r >> 16);
}

#define MFMA16(A, B, C) __builtin_amdgcn_mfma_f32_16x16x32_bf16(A, B, C, 0, 0, 0)

// Generate one 16-wide twiddle tile (cos & sin fragments) for frequency K:
// element (kk, j) = tw((K * (127 + 32kk + 8lh + j)) mod 511),
// tw(p) = (cos(-2pi p/511), sin(-2pi p/511)). K >= 511 -> zeros.
__device__ __forceinline__ void gen_tile(int K, int lh, frag_u* twc, frag_u* tws) {
    if (K >= 511) {
        #pragma unroll
        for (int kk = 0; kk < 8; ++kk) {
            #pragma unroll
            for (int j = 0; j < 8; ++j) { twc[kk].u[j] = 0; tws[kk].u[j] = 0; }
        }
        return;
    }
    const float W = -TWO_PI_F / 511.0f;
    int e0  = (K * (PADOFF + 8 * lh)) % 511;
    int e24 = (24 * K) % 511;
    float c, s, c1, s1, c24, s24;
    __sincosf(W * (float)e0, &s, &c);
    __sincosf(W * (float)K, &s1, &c1);
    __sincosf(W * (float)e24, &s24, &c24);
    #pragma unroll
    for (int kk = 0; kk < 8; ++kk) {
        #pragma unroll
        for (int j = 0; j < 8; ++j) {
            twc[kk].u[j] = f2bf(c);
            tws[kk].u[j] = f2bf(s);
            float cn = c * c1 - s * s1;     // advance b by 1
            s = c * s1 + s * c1; c = cn;
        }
        float cn = c * c24 - s * s24;       // advance b by 24 (to next kk block)
        s = c * s24 + s * c24; c = cn;
    }
}

// ---------------- stage 1: DFT along W (twiddle-stationary) ----------------
// X1[n1][k2] = sum_b src[n1][b] * W[b][k2]; x1t[lc*4+tsel*2+c][k2][n1] bf16.
// grid = 16cc blocks x 256 thr: h = bid&1 (t-half), q = (bid>>1)&3 (row
// quarter), img = bid>>3. Wave w owns t-pair {8h+2w, 8h+2w+1}, generated.
__global__ __launch_bounds__(256, 2) void stage1(const float* __restrict__ target,
                                                 const float* __restrict__ recon,
                                                 u16* __restrict__ x1t,
                                                 float* __restrict__ sacc,
                                                 int c0) {
    int tid = threadIdx.x;
    int w = tid >> 6, l = tid & 63;
    int lm = l & 15, lh = l >> 4;
    int h   = blockIdx.x & 1;
    int q   = (blockIdx.x >> 1) & 3;
    int imgl = blockIdx.x >> 3;          // [0, 2cc)
    if (blockIdx.x == 0 && c0 == 0 && tid < 2 * NCH) sacc[tid] = 0.0f;
    int lc = imgl >> 1;
    int tsel = imgl & 1;
    const float* src = (tsel == 0 ? target : recon) + (size_t)(c0 + lc) * 65536;
    int r0 = 64 * q;

    __shared__ u16 lin[16384];           // 32 KiB: [(s*8+kk)*512 + l*8]

    // ---- stage 64 rows f32 -> bf16 fragments
    {
        int row = tid >> 2;              // 0..63
        int cg  = tid & 3;
        const float* rp = src + (size_t)(r0 + row) * 256 + cg * 64;
        float4 v[16];
        #pragma unroll
        for (int i = 0; i < 16; ++i) v[i] = *(const float4*)(rp + 4 * i);
        u16 b[64];
        #pragma unroll
        for (int i = 0; i < 16; ++i) {
            b[4*i]   = f2bf(v[i].x); b[4*i+1] = f2bf(v[i].y);
            b[4*i+2] = f2bf(v[i].z); b[4*i+3] = f2bf(v[i].w);
        }
        int s = row >> 4, lmw = row & 15;
        #pragma unroll
        for (int i2 = 0; i2 < 8; ++i2) {
            int col0 = cg * 64 + i2 * 8;
            int kk = col0 >> 5, lhw = (col0 >> 3) & 3;
            u16* dst = &lin[((s * 8 + kk) * 512) + (lhw * 16 + lmw) * 8];
            *(s16x8*)dst = *(const s16x8*)&b[i2 * 8];
        }
    }

    // ---- stationary twiddles, generated in registers
    int t0 = 8 * h + 2 * w;
    frag_u tw00[8], tw01[8], tw10[8], tw11[8];   // [t][cos/sin][kk]
    gen_tile(16 * t0 + lm, lh, tw00, tw01);
    gen_tile(16 * (t0 + 1) + lm, lh, tw10, tw11);
    __syncthreads();

    // ---- kk-outer: 4 ds_read feed 16 MFMA (4 subtiles x 4 (t,c))
    f32x4 a00[4], a01[4], a10[4], a11[4];
    #pragma unroll
    for (int s = 0; s < 4; ++s) {
        a00[s] = (f32x4){0,0,0,0}; a01[s] = (f32x4){0,0,0,0};
        a10[s] = (f32x4){0,0,0,0}; a11[s] = (f32x4){0,0,0,0};
    }
    #pragma unroll
    for (int kk = 0; kk < 8; ++kk) {
        s16x8 af[4];
        #pragma unroll
        for (int s = 0; s < 4; ++s)
            af[s] = *(const s16x8*)&lin[((s * 8 + kk) * 512) + l * 8];
        #pragma unroll
        for (int s = 0; s < 4; ++s) {
            a00[s] = MFMA16(af[s], tw00[kk].v, a00[s]);
            a01[s] = MFMA16(af[s], tw01[kk].v, a01[s]);
            a10[s] = MFMA16(af[s], tw10[kk].v, a10[s]);
            a11[s] = MFMA16(af[s], tw11[kk].v, a11[s]);
        }
    }

    // ---- epilogue: D (m=4lh+r, n=lm): n1 = r0+16s+4lh+r, k2 = 16t+lm
    u16* chdst = x1t + (size_t)(lc * 4 + tsel * 2) * 65536;
    #pragma unroll
    for (int s = 0; s < 4; ++s) {
        size_t off0 = (size_t)(16 * t0 + lm) * 256 + r0 + 16 * s + 4 * lh;
        size_t off1 = off0 + 4096;
        ushort4 o;
        o.x = f2bf(a00[s][0]); o.y = f2bf(a00[s][1]);
        o.z = f2bf(a00[s][2]); o.w = f2bf(a00[s][3]);
        *(ushort4*)(chdst + off0) = o;
        o.x = f2bf(a01[s][0]); o.y = f2bf(a01[s][1]);
        o.z = f2bf(a01[s][2]); o.w = f2bf(a01[s][3]);
        *(ushort4*)(chdst + 65536 + off0) = o;
        o.x = f2bf(a10[s][0]); o.y = f2bf(a10[s][1]);
        o.z = f2bf(a10[s][2]); o.w = f2bf(a10[s][3]);
        *(ushort4*)(chdst + off1) = o;
        o.x = f2bf(a11[s][0]); o.y = f2bf(a11[s][1]);
        o.z = f2bf(a11[s][2]); o.w = f2bf(a11[s][3]);
        *(ushort4*)(chdst + 65536 + off1) = o;
    }
}

// ---------------- stage 2: twiddle-stationary, x1t streamed via LDS ----------------
// grid = 64*ngrp x 256 thr: t = bid&15, o = (bid>>4)&3, chg = bid>>6.
// Wave w: kt pair {8o+2w, +1} twiddles generated in VGPRs. 6-channel loop with
// two named LDS buffers; per-channel sums in regs; one reduce at end.
__global__ __launch_bounds__(256, 2) void stage2(const u16* __restrict__ x1t,
                                                 float* __restrict__ sacc,
                                                 int c0, int cc) {
    int tid = threadIdx.x;
    int w = tid >> 6, l = tid & 63;
    int lm = l & 15, lh = l >> 4;
    int t   = blockIdx.x & 15;
    int o   = (blockIdx.x >> 4) & 3;
    int chg = blockIdx.x >> 6;
    int ch0 = chg * 6;
    int nch = cc - ch0; if (nch > 6) nch = 6;
    if (nch <= 0) return;

    __shared__ u16 sbufA[16384];
    __shared__ u16 sbufB[16384];
    __shared__ float red[4][12];

    int kt0 = 8 * o + 2 * w;
    frag_u twr0[8], twi0[8], twr1[8], twi1[8];
    gen_tile(16 * kt0 + lm, lh, twr0, twi0);
    gen_tile(16 * (kt0 + 1) + lm, lh, twr1, twi1);

    int k2 = 16 * t + lm;
    float wgt = (k2 == 0) ? 1.f : 2.f;
    int rowoff = (16 * t + lm) * 256 + 8 * lh;
    float s1a[6] = {0,0,0,0,0,0}, s2a[6] = {0,0,0,0,0,0};

#define STAGE(BUF, LC) do {                                                   \
    const u16* cb_ = x1t + (size_t)(4 * (LC)) * 65536;                        \
    _Pragma("unroll")                                                         \
    for (int q_ = 0; q_ < 8; ++q_) {                                          \
        int pair_ = w * 8 + q_;                                               \
        int p_ = pair_ >> 3, kk_ = pair_ & 7;                                 \
        const u16* g_ = cb_ + (size_t)p_ * 65536 + rowoff + 32 * kk_;         \
        __builtin_amdgcn_global_load_lds((gas_p)g_,                           \
            (las_p)&BUF[pair_ * 512], 16, 0, 0);                              \
    } } while (0)

#define COMPUTE(BUF, I) do {                                                  \
    f32x4 c0rr = {0,0,0,0}, c0ii = {0,0,0,0}, c0ri = {0,0,0,0}, c0ir = {0,0,0,0}; \
    f32x4 d0rr = {0,0,0,0}, d0ii = {0,0,0,0}, d0ri = {0,0,0,0}, d0ir = {0,0,0,0}; \
    f32x4 c1rr = {0,0,0,0}, c1ii = {0,0,0,0}, c1ri = {0,0,0,0}, c1ir = {0,0,0,0}; \
    f32x4 d1rr = {0,0,0,0}, d1ii = {0,0,0,0}, d1ri = {0,0,0,0}, d1ir = {0,0,0,0}; \
    _Pragma("unroll")                                                         \
    for (int kk = 0; kk < 8; ++kk) {                                          \
        const u16* fb = &BUF[kk * 512 + l * 8];                               \
        s16x8 ar = *(const s16x8*)(fb);                                       \
        s16x8 ai = *(const s16x8*)(fb + 4096);                                \
        s16x8 br = *(const s16x8*)(fb + 8192);                                \
        s16x8 bi = *(const s16x8*)(fb + 12288);                               \
        c0rr = MFMA16(twr0[kk].v, ar, c0rr);                                  \
        c0ii = MFMA16(twi0[kk].v, ai, c0ii);                                  \
        c0ri = MFMA16(twr0[kk].v, ai, c0ri);                                  \
        c0ir = MFMA16(twi0[kk].v, ar, c0ir);                                  \
        d0rr = MFMA16(twr0[kk].v, br, d0rr);                                  \
        d0ii = MFMA16(twi0[kk].v, bi, d0ii);                                  \
        d0ri = MFMA16(twr0[kk].v, bi, d0ri);                                  \
        d0ir = MFMA16(twi0[kk].v, br, d0ir);                                  \
        c1rr = MFMA16(twr1[kk].v, ar, c1rr);                                  \
        c1ii = MFMA16(twi1[kk].v, ai, c1ii);                                  \
        c1ri = MFMA16(twr1[kk].v, ai, c1ri);                                  \
        c1ir = MFMA16(twi1[kk].v, ar, c1ir);                                  \
        d1rr = MFMA16(twr1[kk].v, br, d1rr);                                  \
        d1ii = MFMA16(twi1[kk].v, bi, d1ii);                                  \
        d1ri = MFMA16(twr1[kk].v, bi, d1ri);                                  \
        d1ir = MFMA16(twi1[kk].v, br, d1ir);                                  \
    }                                                                         \
    _Pragma("unroll")                                                         \
    for (int r = 0; r < 4; ++r) {                                             \
        {                                                                     \
            float Xr = c0rr[r] - c0ii[r], Xi = c0ri[r] + c0ir[r];             \
            float Yr = d0rr[r] - d0ii[r], Yi = d0ri[r] + d0ir[r];             \
            float Pr = Xr * Yr + Xi * Yi;                                     \
            float Pi = Xr * Yi - Xi * Yr;                                     \
            float Q  = Xr * Xr + Xi * Xi;                                     \
            float inv = 1.0f / (Q * Q + 1e-30f);                              \
            s1a[I] += wgt * Pr * Q * inv;                                     \
            s2a[I] += wgt * (Pr * Pr + Pi * Pi) * inv;                        \
        }                                                                     \
        {                                                                     \
            int k1 = 16 * (kt0 + 1) + 4 * lh + r;                             \
            float wg2 = (k1 < 511) ? wgt : 0.f;                               \
            float Xr = c1rr[r] - c1ii[r], Xi = c1ri[r] + c1ir[r];             \
            float Yr = d1rr[r] - d1ii[r], Yi = d1ri[r] + d1ir[r];             \
            float Pr = Xr * Yr + Xi * Yi;                                     \
            float Pi = Xr * Yi - Xi * Yr;                                     \
            float Q  = Xr * Xr + Xi * Xi;                                     \
            float inv = 1.0f / (Q * Q + 1e-30f);                              \
            s1a[I] += wg2 * Pr * Q * inv;                                     \
            s2a[I] += wg2 * (Pr * Pr + Pi * Pi) * inv;                        \
        }                                                                     \
    } } while (0)

    STAGE(sbufA, ch0);
    __syncthreads();

    #pragma unroll
    for (int i = 0; i < 6; i += 2) {
        if (i >= nch) break;
        if (i + 1 < nch) STAGE(sbufB, ch0 + i + 1);
        COMPUTE(sbufA, i);
        __syncthreads();
        if (i + 1 < nch) {
            if (i + 2 < nch) STAGE(sbufA, ch0 + i + 2);
            COMPUTE(sbufB, i + 1);
            __syncthreads();
        }
    }
#undef STAGE
#undef COMPUTE

    #pragma unroll
    for (int i = 0; i < 6; ++i) {
        #pragma unroll
        for (int off = 32; off > 0; off >>= 1) {
            s1a[i] += __shfl_down(s1a[i], off);
            s2a[i] += __shfl_down(s2a[i], off);
        }
    }
    if (l == 0) {
        #pragma unroll
        for (int i = 0; i < 6; ++i) {
            red[w][2 * i]     = s1a[i];
            red[w][2 * i + 1] = s2a[i];
        }
    }
    __syncthreads();
    if (tid < 12) {
        int i = tid >> 1;
        if (i < nch) {
            float v = red[0][tid] + red[1][tid] + red[2][tid] + red[3][tid];
            atomicAdd(&sacc[(tid & 1) * NCH + c0 + ch0 + i], v);
        }
    }
}

__global__ void finalize(const float* __restrict__ s, float* __restrict__ out) {
    int t = threadIdx.x;
    float v = 0.f;
    if (t < NCH) {
        float s1 = s[t], s2 = s[NCH + t];
        v = (s2 != 0.f) ? (s1 * s1) / s2 : 0.f;
    }
    for (int off = 32; off > 0; off >>= 1) v += __shfl_down(v, off);
    if (t == 0) out[0] = 24.0f - 0.5f * v / 261121.0f;
}

// ---------------- launch ----------------
extern "C" void kernel_launch(void* const* d_in, const int* in_sizes, int n_in,
                              void* d_out, int out_size, void* d_ws, size_t ws_size,
                              hipStream_t stream) {
    const float* recon  = (const float*)d_in[0];
    const float* target = (const float*)d_in[1];
    float* out = (float*)d_out;
    char* ws = (char*)d_ws;

    float* sacc = (float*)ws;                        // 512 B
    u16*   x1t  = (u16*)(ws + 512);

    const size_t perch = 4ull * 65536 * 2;           // 512 KiB per channel
    size_t avail = (ws_size > 512) ? ws_size - 512 : 0;
    int chunk = (int)(avail / perch);
    if (chunk > NCH) chunk = NCH;
    if (chunk < 1) chunk = 1;

    for (int c0 = 0; c0 < NCH; c0 += chunk) {
        int cc = (NCH - c0 < chunk) ? (NCH - c0) : chunk;
        int ngrp = (cc + 5) / 6;
        stage1<<<dim3(16 * cc), dim3(256), 0, stream>>>(target, recon, x1t, sacc, c0);
        stage2<<<dim3(64 * ngrp), dim3(256), 0, stream>>>(x1t, sacc, c0, cc);
    }
    finalize<<<dim3(1), dim3(64), 0, stream>>>(sacc, out);
}